// Round 7
// baseline (362.940 us; speedup 1.0000x reference)
//
#include <hip/hip_runtime.h>
#include <hip/hip_bf16.h>
#include <stdint.h>

#define NTOT 65536   // B * N_NODE
#define NNODE 2048
#define CIN 12

__device__ __forceinline__ float bf2f(uint32_t u) {
    union { uint32_t i; float f; } v; v.i = u << 16; return v.f;
}
__device__ __forceinline__ uint16_t f2bf(float f) {
    union { float f; uint32_t i; } v; v.f = f;
    uint32_t x = v.i;
    uint32_t r = x + 0x7fffu + ((x >> 16) & 1u);
    return (uint16_t)(r >> 16);
}
__device__ __forceinline__ float bflo(uint32_t u) { return bf2f(u & 0xffffu); }
__device__ __forceinline__ float bfhi(uint32_t u) { return bf2f(u >> 16); }
__device__ __forceinline__ float sigmf(float x) {
    return __builtin_amdgcn_rcpf(1.0f + __expf(-x));
}
__device__ __forceinline__ float tanhfast(float x) {
    float ex = __expf(2.0f * x);
    return 1.0f - 2.0f * __builtin_amdgcn_rcpf(ex + 1.0f);
}
__device__ __forceinline__ float lrelu(float v) { return v > 0.f ? v : 0.2f * v; }

// non-temporal helpers (streaming data must not evict the gather table from L2)
__device__ __forceinline__ int   ntl_i(const int* p)   { return __builtin_nontemporal_load(p); }
__device__ __forceinline__ float ntl_f(const float* p) { return __builtin_nontemporal_load(p); }
__device__ __forceinline__ void  nts_f(float* p, float v) { __builtin_nontemporal_store(v, p); }
__device__ __forceinline__ void  nts_i(int* p, int v)     { __builtin_nontemporal_store(v, p); }

// ws float offsets (flags[0]=bf16?, flags[1]=edge stride words, flags[2]=gcount)
#define O_WG   16
#define O_AS   1168
#define O_AD   1264
#define O_BIAS 1360
#define O_BIH1 1376
#define O_BHH1 1504
#define O_BIH2 1632
#define O_BHH2 2144
#define O_BLIN 2656
#define O_P    21088   // P[h*12+k] = sum_c Wg[k,h*12+c]*att_src[h,c]  (96 floats)
#define O_END  21184

__device__ __forceinline__ void cvt(const void* s, float* d, int i, int bf) {
    d[i] = bf ? bf2f(((const uint16_t*)s)[i]) : ((const float*)s)[i];
}

// ---------- fused: dtype detect + small-tensor conv + zero ----------
__global__ void __launch_bounds__(256) k_pre(
    const void* x, const int* __restrict__ e32,
    const void* wg, const void* as_, const void* ad_, const void* bs,
    const void* b1, const void* bb1, const void* b2, const void* bb2,
    const void* bl, float* __restrict__ ws, int* __restrict__ deg) {
    int tid = threadIdx.x, lane = tid & 63;
    uint32_t u = ((const uint16_t*)x)[2 * lane];
    uint32_t ex = (u >> 7) & 0xFF;
    bool sane = (ex >= 0x60 && ex <= 0x9F) || (u == 0);
    unsigned long long bsx = __ballot(sane);
    bool hi_zero = (e32[2 * lane + 1] == 0);
    unsigned long long bz = __ballot(hi_zero);
    int bf = (__popcll(bsx) >= 52) ? 1 : 0;
    int st = (__popcll(bz) == 64) ? 2 : 1;
    if (blockIdx.x == 0 && tid == 0) {
        ((int*)ws)[0] = bf; ((int*)ws)[1] = st; ((int*)ws)[2] = 0;
    }
    deg[blockIdx.x * 256 + tid] = 0;
    int i = blockIdx.x * 256 + tid;
    if (i < 1152)  { cvt(wg,  ws + O_WG,   i, bf); return; } i -= 1152;
    if (i < 96)    { cvt(as_, ws + O_AS,   i, bf); return; } i -= 96;
    if (i < 96)    { cvt(ad_, ws + O_AD,   i, bf); return; } i -= 96;
    if (i < 12)    { cvt(bs,  ws + O_BIAS, i, bf); return; } i -= 12;
    if (i < 128)   { cvt(b1,  ws + O_BIH1, i, bf); return; } i -= 128;
    if (i < 128)   { cvt(bb1, ws + O_BHH1, i, bf); return; } i -= 128;
    if (i < 512)   { cvt(b2,  ws + O_BIH2, i, bf); return; } i -= 512;
    if (i < 512)   { cvt(bb2, ws + O_BHH2, i, bf); return; } i -= 512;
    if (i < 18432) { cvt(bl,  ws + O_BLIN, i, bf); }
}

// ---------- fused attention scores + edge histogram + packed x record ----------
__global__ void __launch_bounds__(256) k_nfa(const void* __restrict__ xraw,
                                             const float* __restrict__ Wg,
                                             const float* __restrict__ att,
                                             const int* __restrict__ flags,
                                             const int* __restrict__ e, int E,
                                             int* __restrict__ deg, int* __restrict__ rank,
                                             float* __restrict__ a_s, float* __restrict__ a_d,
                                             float* __restrict__ rec) {
    __shared__ float sx[384];
    __shared__ float sw[1152];
    __shared__ float satt[192];
    __shared__ float sh[3072];
    int tid = threadIdx.x;
    int n0 = blockIdx.x * 32;
    int bf = flags[0];
    if (bf) {
        const uint32_t* xp = (const uint32_t*)xraw;
        uint32_t* rx = (uint32_t*)rec;
        for (int i = tid; i < 192; i += 256) {
            uint32_t u = xp[n0 * 6 + i];
            sx[2 * i] = bflo(u); sx[2 * i + 1] = bfhi(u);
            rx[(size_t)(n0 + i / 6) * 8 + i % 6] = u;  // pack x into 32B record
        }
    } else {
        const float* xp = (const float*)xraw;
        for (int i = tid; i < 384; i += 256) sx[i] = xp[n0 * 12 + i];
    }
    for (int i = tid; i < 1152; i += 256) sw[i] = Wg[i];
    if (tid < 192) satt[tid] = att[tid];
    {
        long st = flags[1];
        int chunk = (E + gridDim.x - 1) / gridDim.x;
        int ebase = blockIdx.x * chunk;
        int eend = min(ebase + chunk, E);
        for (int i = ebase + tid; i < eend; i += 256) {
            int d = ntl_i(e + st * (E + i));
            rank[i] = atomicAdd(&deg[d], 1);
        }
    }
    __syncthreads();
#pragma unroll
    for (int r = 0; r < 12; r++) {
        int idx = r * 256 + tid;
        int n = idx / 96, o = idx % 96;
        float acc = 0.f;
#pragma unroll
        for (int k = 0; k < 12; k++) acc += sx[n * 12 + k] * sw[k * 96 + o];
        sh[idx] = acc;
    }
    __syncthreads();
    {
        int nl = tid >> 3, h = tid & 7;
        const float* hr = sh + nl * 96 + h * 12;
        float s = 0.f, dd = 0.f;
#pragma unroll
        for (int c = 0; c < 12; c++) {
            float v = hr[c];
            s += v * satt[h * 12 + c];
            dd += v * satt[96 + h * 12 + c];
        }
        if (!bf) a_s[n0 * 8 + tid] = s;   // f32 fallback path only
        a_d[n0 * 8 + tid] = dd;
    }
}

// ---------- scan: local exclusive scan + atomic global base (+ P fold) ----------
__global__ void k_scan(const int* __restrict__ deg, int* __restrict__ offs,
                       int* __restrict__ gcount,
                       const float* __restrict__ wg, const float* __restrict__ att,
                       float* __restrict__ P) {
    __shared__ int s[256];
    __shared__ int base;
    int t = threadIdx.x, i = blockIdx.x * 256 + t;
    if (blockIdx.x == 0 && t < 96) {     // fold Wg*att_src -> P[h*12+k]
        int h = t / 12, k = t % 12;
        float p = 0.f;
#pragma unroll
        for (int c = 0; c < 12; c++) p += wg[k * 96 + h * 12 + c] * att[h * 12 + c];
        P[h * 12 + k] = p;
    }
    int v = deg[i];
    s[t] = v; __syncthreads();
    for (int off = 1; off < 256; off <<= 1) {
        int a = (t >= off) ? s[t - off] : 0;
        __syncthreads();
        s[t] += a;
        __syncthreads();
    }
    if (t == 255) base = atomicAdd(gcount, s[255]);
    __syncthreads();
    offs[i] = base + s[t] - v;
}

__global__ void k_scatter(const int* __restrict__ e, int E, const int* __restrict__ flags,
                          const int* __restrict__ offs, const int* __restrict__ rank,
                          int* __restrict__ ssrc) {
    int i = blockIdx.x * 256 + threadIdx.x;
    if (i < E) {
        long st = flags[1];
        int s = ntl_i(e + st * i);
        int d = ntl_i(e + st * (E + i));
        nts_i(ssrc + offs[d] + rank[i], s);
    }
}

// ---------- per-edge helper: unpack record, score, accumulate ----------
__device__ __forceinline__ void agg_edge(uint4 xu, uint2 xv, const float* pv,
                                         float adh, bool valid,
                                         float& wsum, float* acc) {
    float xf[12];
    xf[0] = bflo(xu.x); xf[1] = bfhi(xu.x); xf[2] = bflo(xu.y); xf[3] = bfhi(xu.y);
    xf[4] = bflo(xu.z); xf[5] = bfhi(xu.z); xf[6] = bflo(xu.w); xf[7] = bfhi(xu.w);
    xf[8] = bflo(xv.x); xf[9] = bfhi(xv.x); xf[10] = bflo(xv.y); xf[11] = bfhi(xv.y);
    float asv = 0.f;
#pragma unroll
    for (int c = 0; c < 12; c++) asv += xf[c] * pv[c];
    float w = __expf(lrelu(asv + adh));
    if (!valid) w = 0.f;
    wsum += w;
#pragma unroll
    for (int c = 0; c < 12; c++) acc[c] += w * xf[c];
}

// ---------- GAT aggregation: depth-2 pipelined 32B-record gather ----------
__global__ void __launch_bounds__(256) k_agg(
    const void* __restrict__ xraw, const float* __restrict__ WgG,
    const float* __restrict__ a_s, const float* __restrict__ a_d,
    const int* __restrict__ offs, const int* __restrict__ deg,
    const int* __restrict__ ssrc, const float* __restrict__ bias,
    const int* __restrict__ flags, const float* __restrict__ rec,
    const float* __restrict__ P, float* __restrict__ gT) {
    __shared__ float swg[1152];
    __shared__ float sres[4][12];
    int tid = threadIdx.x, wave = tid >> 6, lane = tid & 63;
    for (int i = tid; i < 1152; i += 256) swg[i] = WgG[i];
    __syncthreads();
    int node = blockIdx.x * 4 + wave;
    int beg = offs[node], d = deg[node];
    int sub = lane >> 3, h = lane & 7;
    float adh = ntl_f(a_d + node * 8 + h);
    int bf = flags[0];
    float acc[12];
    float wsum = 0.f;
#pragma unroll
    for (int c = 0; c < 12; c++) acc[c] = 0.f;
    if (bf) {
        float pv[12];
        {
            const float4* pp = (const float4*)(P + h * 12);
            float4 p0 = pp[0], p1 = pp[1], p2 = pp[2];
            pv[0] = p0.x; pv[1] = p0.y; pv[2] = p0.z; pv[3] = p0.w;
            pv[4] = p1.x; pv[5] = p1.y; pv[6] = p1.z; pv[7] = p1.w;
            pv[8] = p2.x; pv[9] = p2.y; pv[10] = p2.z; pv[11] = p2.w;
        }
        // self loop from own record
        if (sub == 0) {
            const uint32_t* rp0 = (const uint32_t*)rec + (size_t)node * 8;
            uint4 xu = *(const uint4*)rp0;
            uint2 xv = *(const uint2*)(rp0 + 4);
            agg_edge(xu, xv, pv, adh, true, wsum, acc);
        }
        if (d > 0) {
            const uint32_t* rb = (const uint32_t*)rec;
            // depth-2 software pipeline: two 8-edge groups in flight per lane
            int s0 = ntl_i(ssrc + beg + min(sub, d - 1));
            const uint32_t* rp0 = rb + (size_t)s0 * 8;
            uint4 xu0 = *(const uint4*)rp0; uint2 xv0 = *(const uint2*)(rp0 + 4);
            int s1 = ntl_i(ssrc + beg + min(sub + 8, d - 1));
            const uint32_t* rp1 = rb + (size_t)s1 * 8;
            uint4 xu1 = *(const uint4*)rp1; uint2 xv1 = *(const uint2*)(rp1 + 4);
            for (int base = 0; base < d; base += 16) {
                int s2 = ntl_i(ssrc + beg + min(base + 16 + sub, d - 1));
                const uint32_t* rp2 = rb + (size_t)s2 * 8;
                uint4 xu2 = *(const uint4*)rp2; uint2 xv2 = *(const uint2*)(rp2 + 4);
                int s3 = ntl_i(ssrc + beg + min(base + 24 + sub, d - 1));
                const uint32_t* rp3 = rb + (size_t)s3 * 8;
                uint4 xu3 = *(const uint4*)rp3; uint2 xv3 = *(const uint2*)(rp3 + 4);
                agg_edge(xu0, xv0, pv, adh, base + sub < d, wsum, acc);
                agg_edge(xu1, xv1, pv, adh, base + 8 + sub < d, wsum, acc);
                xu0 = xu2; xv0 = xv2; xu1 = xu3; xv1 = xv3;
            }
        }
    } else {
        // legacy f32 path
        if (sub == 0) {
            float w = __expf(lrelu(a_s[node * 8 + h] + adh));
            wsum = w;
            const float4* xp = (const float4*)((const float*)xraw + node * 12);
            float4 v0 = xp[0], v1 = xp[1], v2 = xp[2];
            acc[0] = w * v0.x; acc[1] = w * v0.y; acc[2] = w * v0.z; acc[3] = w * v0.w;
            acc[4] = w * v1.x; acc[5] = w * v1.y; acc[6] = w * v1.z; acc[7] = w * v1.w;
            acc[8] = w * v2.x; acc[9] = w * v2.y; acc[10] = w * v2.z; acc[11] = w * v2.w;
        }
        for (int base = 0; base < d; base += 8) {
            int k = base + sub;
            if (k < d) {
                int s = ssrc[beg + k];
                float w = __expf(lrelu(a_s[s * 8 + h] + adh));
                wsum += w;
                const float4* xp = (const float4*)((const float*)xraw + s * 12);
                float4 v0 = xp[0], v1 = xp[1], v2 = xp[2];
                acc[0] += w * v0.x; acc[1] += w * v0.y; acc[2] += w * v0.z; acc[3] += w * v0.w;
                acc[4] += w * v1.x; acc[5] += w * v1.y; acc[6] += w * v1.z; acc[7] += w * v1.w;
                acc[8] += w * v2.x; acc[9] += w * v2.y; acc[10] += w * v2.z; acc[11] += w * v2.w;
            }
        }
    }
#pragma unroll
    for (int off = 8; off <= 32; off <<= 1) {
        wsum += __shfl_xor(wsum, off, 64);
#pragma unroll
        for (int c = 0; c < 12; c++) acc[c] += __shfl_xor(acc[c], off, 64);
    }
    float invw = 1.f / wsum;
#pragma unroll
    for (int c = 0; c < 12; c++) acc[c] *= invw;
    float p0 = 0.f, p1 = 0.f;
    const float* wcol = swg + h * 12;
#pragma unroll
    for (int k = 0; k < 12; k++) {
        float a = acc[k];
        p0 += a * wcol[k * 96 + sub];
        p1 += a * wcol[k * 96 + sub + 4];
    }
#pragma unroll
    for (int off = 1; off <= 4; off <<= 1) {
        p0 += __shfl_xor(p0, off, 64);
        p1 += __shfl_xor(p1, off, 64);
    }
    if (h == 0) {
        sres[wave][sub] = p0;
        if (sub >= 4) sres[wave][sub + 4] = p1;
    }
    __syncthreads();
    if (tid < 48) {
        int no = tid / 12, c = tid % 12;
        nts_f(gT + c * NTOT + blockIdx.x * 4 + no, sres[no][c] * 0.125f + bias[c]);
    }
}

// ---------- Z1: one (t, batch) per block -> 384 blocks (was 96: 2/3 of device idle) ----------
__global__ void __launch_bounds__(256) k_z1(const float* __restrict__ gT,
                                            const void* __restrict__ Wraw,
                                            const float* __restrict__ b1,
                                            const float* __restrict__ b2,
                                            const int* __restrict__ flags,
                                            float* __restrict__ Z1) {
    int t = blockIdx.x >> 5, b = blockIdx.x & 31;
    __shared__ float sv[2048];
    __shared__ float zp[2][128];
    int tid = threadIdx.x;
    for (int v = tid; v < 2048; v += 256) sv[v] = ntl_f(gT + t * NTOT + b * NNODE + v);
    __syncthreads();
    int row = tid & 127, half = tid >> 7;
    float a = 0.f;
    int hbase = half * 1024;
    if (flags[0]) {
        const uint4* wp = (const uint4*)((const uint16_t*)Wraw + row * 2048 + hbase);
        for (int k = 0; k < 128; k++) {
            uint4 u = wp[k];
            float w0 = bflo(u.x), w1 = bfhi(u.x), w2 = bflo(u.y), w3 = bfhi(u.y);
            float w4 = bflo(u.z), w5 = bfhi(u.z), w6 = bflo(u.w), w7 = bfhi(u.w);
            float4 A = *(const float4*)&sv[hbase + 8 * k];
            float4 B = *(const float4*)&sv[hbase + 8 * k + 4];
            a += w0 * A.x + w1 * A.y + w2 * A.z + w3 * A.w
               + w4 * B.x + w5 * B.y + w6 * B.z + w7 * B.w;
        }
    } else {
        const float4* wp = (const float4*)((const float*)Wraw + row * 2048 + hbase);
        for (int k = 0; k < 256; k++) {
            float4 w = wp[k];
            float4 A = *(const float4*)&sv[hbase + 4 * k];
            a += w.x * A.x + w.y * A.y + w.z * A.z + w.w * A.w;
        }
    }
    zp[half][row] = a;
    __syncthreads();
    if (tid < 128)
        Z1[t * 4096 + b * 128 + tid] = zp[0][tid] + zp[1][tid] + b1[tid] + b2[tid];
}

// ---------- LSTM1: one block (64 thr) per batch, fully unrolled ----------
__global__ void __launch_bounds__(64) k_lstm1(
    const float* __restrict__ Z1, const void* __restrict__ Whh1r,
    const int* __restrict__ flags, float* __restrict__ h1g) {
    int b = blockIdx.x, l = threadIdx.x;
    __shared__ __align__(16) float hb1[32];
    int bf = flags[0];
    float wA[32], wB[32];
    if (bf) {
        const uint32_t* w1 = (const uint32_t*)Whh1r;
#pragma unroll
        for (int k = 0; k < 16; k++) {
            uint32_t u = w1[l * 16 + k];
            wA[2 * k] = bflo(u); wA[2 * k + 1] = bfhi(u);
            uint32_t v = w1[(l + 64) * 16 + k];
            wB[2 * k] = bflo(v); wB[2 * k + 1] = bfhi(v);
        }
    } else {
        const float* w1 = (const float*)Whh1r;
#pragma unroll
        for (int k = 0; k < 32; k++) {
            wA[k] = w1[l * 32 + k];
            wB[k] = w1[(l + 64) * 32 + k];
        }
    }
    float za[12], zg[12];
#pragma unroll
    for (int t = 0; t < 12; t++) {
        za[t] = Z1[t * 4096 + b * 128 + l];
        zg[t] = Z1[t * 4096 + b * 128 + 64 + l];
    }
    if (l < 32) hb1[l] = 0.f;
    __builtin_amdgcn_wave_barrier();
    float c = 0.f;
#pragma unroll
    for (int t = 0; t < 12; t++) {
        float d0 = za[t], d1 = zg[t];
#pragma unroll
        for (int k = 0; k < 8; k++) {
            float4 h4 = *(const float4*)&hb1[4 * k];
            d0 += wA[4*k]*h4.x + wA[4*k+1]*h4.y + wA[4*k+2]*h4.z + wA[4*k+3]*h4.w;
            d1 += wB[4*k]*h4.x + wB[4*k+1]*h4.y + wB[4*k+2]*h4.z + wB[4*k+3]*h4.w;
        }
        float e0 = __shfl_xor(d0, 32, 64);
        float e1 = __shfl_xor(d1, 32, 64);
        if (l < 32) {
            c = sigmf(e0) * c + sigmf(d0) * tanhfast(d1);
            float h = sigmf(e1) * tanhfast(c);
            hb1[l] = h;
            h1g[t * 1024 + b * 32 + l] = h;
        }
        __builtin_amdgcn_wave_barrier();
    }
}

// ---------- Wih2 projection: t-parallel, one row per thread ----------
__global__ void __launch_bounds__(512) k_wih2(
    const float* __restrict__ h1g, const void* __restrict__ Wih2r,
    const float* __restrict__ b2i, const float* __restrict__ b2h,
    const int* __restrict__ flags, float* __restrict__ z2g) {
    int tb = blockIdx.x;              // t*32 + b
    int t = tb >> 5, b = tb & 31;
    int r = threadIdx.x;              // 0..511
    __shared__ __align__(16) float h[32];
    if (r < 32) h[r] = h1g[t * 1024 + b * 32 + r];
    __syncthreads();
    float z = b2i[r] + b2h[r];
    const float4* hp = (const float4*)h;
    if (flags[0]) {
        const uint4* wp = (const uint4*)((const uint16_t*)Wih2r + r * 32);
#pragma unroll
        for (int k = 0; k < 4; k++) {
            uint4 u = wp[k];
            float4 h0 = hp[2 * k], h1 = hp[2 * k + 1];
            z += bflo(u.x)*h0.x + bfhi(u.x)*h0.y + bflo(u.y)*h0.z + bfhi(u.y)*h0.w
               + bflo(u.z)*h1.x + bfhi(u.z)*h1.y + bflo(u.w)*h1.z + bfhi(u.w)*h1.w;
        }
    } else {
        const float4* wp = (const float4*)((const float*)Wih2r + r * 32);
#pragma unroll
        for (int k = 0; k < 8; k++) {
            float4 w = wp[k];
            float4 h4 = hp[k];
            z += w.x*h4.x + w.y*h4.y + w.z*h4.z + w.w*h4.w;
        }
    }
    z2g[t * 16384 + b * 512 + r] = z;
}

// ---------- LSTM2: one block (512 thr) per batch, f32-pinned weights ----------
__global__ void __launch_bounds__(512, 1) k_lstm2(
    const float* __restrict__ z2g, const void* __restrict__ Whh2r,
    const int* __restrict__ flags, float* __restrict__ h2l) {
    int b = blockIdx.x, tid = threadIdx.x;
    __shared__ __align__(16) float hb[2][128];
    int bf = flags[0];
    int lane = tid & 63, wv = tid >> 6;
    int kh = lane >> 5;
    int gp = (lane >> 4) & 1;
    int e = wv * 16 + (lane & 15);
    int rA = gp * 256 + e;
    int rB = gp * 256 + 128 + e;

    float wA[64], wB[64];
    if (bf) {
        const uint16_t* W2 = (const uint16_t*)Whh2r;
        const uint4* pA = (const uint4*)(W2 + rA * 128 + kh * 64);
        const uint4* pB = (const uint4*)(W2 + rB * 128 + kh * 64);
#pragma unroll
        for (int k = 0; k < 8; k++) {
            uint4 ua = pA[k], ub = pB[k];
            wA[8*k+0] = bflo(ua.x); wA[8*k+1] = bfhi(ua.x);
            wA[8*k+2] = bflo(ua.y); wA[8*k+3] = bfhi(ua.y);
            wA[8*k+4] = bflo(ua.z); wA[8*k+5] = bfhi(ua.z);
            wA[8*k+6] = bflo(ua.w); wA[8*k+7] = bfhi(ua.w);
            wB[8*k+0] = bflo(ub.x); wB[8*k+1] = bfhi(ub.x);
            wB[8*k+2] = bflo(ub.y); wB[8*k+3] = bfhi(ub.y);
            wB[8*k+4] = bflo(ub.z); wB[8*k+5] = bfhi(ub.z);
            wB[8*k+6] = bflo(ub.w); wB[8*k+7] = bfhi(ub.w);
        }
    } else {
        const float4* pA = (const float4*)((const float*)Whh2r + rA * 128 + kh * 64);
        const float4* pB = (const float4*)((const float*)Whh2r + rB * 128 + kh * 64);
#pragma unroll
        for (int k = 0; k < 16; k++) {
            float4 a = pA[k], c = pB[k];
            wA[4*k+0] = a.x; wA[4*k+1] = a.y; wA[4*k+2] = a.z; wA[4*k+3] = a.w;
            wB[4*k+0] = c.x; wB[4*k+1] = c.y; wB[4*k+2] = c.z; wB[4*k+3] = c.w;
        }
    }
    if (tid < 128) hb[0][tid] = 0.f;
    const float* zb = z2g + b * 512;
    float zA = 0.f, zB = 0.f;
    if (kh == 0) { zA = zb[rA]; zB = zb[rB]; }
    float c2 = 0.f;
    __syncthreads();
#pragma unroll 1
    for (int t = 0; t < 12; t++) {
        float nA = 0.f, nB = 0.f;
        if (t < 11 && kh == 0) {       // prefetch next step's z (L2-hit)
            nA = zb[(t + 1) * 16384 + rA];
            nB = zb[(t + 1) * 16384 + rB];
        }
        const float4* hp = (const float4*)&hb[t & 1][kh * 64];
        float pA = zA, pB = zB;
#pragma unroll
        for (int k = 0; k < 16; k++) {
            float4 h4 = hp[k];
            pA += wA[4*k]*h4.x + wA[4*k+1]*h4.y + wA[4*k+2]*h4.z + wA[4*k+3]*h4.w;
            pB += wB[4*k]*h4.x + wB[4*k+1]*h4.y + wB[4*k+2]*h4.z + wB[4*k+3]*h4.w;
        }
        float sA = pA + __shfl_xor(pA, 32, 64);
        float sB = pB + __shfl_xor(pB, 32, 64);
        float zg_ = __shfl_xor(sA, 16, 64);
        float zo_ = __shfl_xor(sB, 16, 64);
        if (gp == 0) {
            c2 = sigmf(sB) * c2 + sigmf(sA) * tanhfast(zg_);
            float hh = sigmf(zo_) * tanhfast(c2);
            if (kh == 0) {
                hb[(t & 1) ^ 1][e] = hh;
                if (t == 11) h2l[b * 128 + e] = hh;
            }
        }
        __syncthreads();
        zA = nA; zB = nB;
    }
}

// ---------- final linear (dual-path W) ----------
__global__ void __launch_bounds__(256) k_lin(const float* __restrict__ h2l,
                                             const void* __restrict__ Wraw,
                                             const float* __restrict__ bl,
                                             const int* __restrict__ flags,
                                             void* __restrict__ outv) {
    __shared__ float hl[8 * 128];
    int bg = blockIdx.y;
    for (int i = threadIdx.x; i < 1024; i += 256) hl[i] = h2l[bg * 1024 + i];
    __syncthreads();
    int o = blockIdx.x * 256 + threadIdx.x;
    float bb = bl[o];
    float acc[8];
#pragma unroll
    for (int b = 0; b < 8; b++) acc[b] = bb;
    int bf = flags[0];
    if (bf) {
        const uint4* wp = (const uint4*)((const uint16_t*)Wraw + o * 128);
        for (int k = 0; k < 16; k++) {
            uint4 u = wp[k];
            float w0 = bflo(u.x), w1 = bfhi(u.x), w2 = bflo(u.y), w3 = bfhi(u.y);
            float w4 = bflo(u.z), w5 = bfhi(u.z), w6 = bflo(u.w), w7 = bfhi(u.w);
#pragma unroll
            for (int b = 0; b < 8; b++) {
                const float* h8 = hl + b * 128 + k * 8;
                acc[b] += w0 * h8[0] + w1 * h8[1] + w2 * h8[2] + w3 * h8[3]
                        + w4 * h8[4] + w5 * h8[5] + w6 * h8[6] + w7 * h8[7];
            }
        }
    } else {
        const float4* wp = (const float4*)((const float*)Wraw + o * 128);
        for (int k = 0; k < 32; k++) {
            float4 w = wp[k];
#pragma unroll
            for (int b = 0; b < 8; b++) {
                const float* h4 = hl + b * 128 + k * 4;
                acc[b] += w.x * h4[0] + w.y * h4[1] + w.z * h4[2] + w.w * h4[3];
            }
        }
    }
    if (bf) {
        uint16_t* out = (uint16_t*)outv;
#pragma unroll
        for (int b = 0; b < 8; b++) out[(bg * 8 + b) * 18432 + o] = f2bf(acc[b]);
    } else {
        float* out = (float*)outv;
#pragma unroll
        for (int b = 0; b < 8; b++) out[(bg * 8 + b) * 18432 + o] = acc[b];
    }
}

extern "C" void kernel_launch(void* const* d_in, const int* in_sizes, int n_in,
                              void* d_out, int out_size, void* d_ws, size_t ws_size,
                              hipStream_t stream) {
    int E = in_sizes[1] / 2;

    float* ws = (float*)d_ws;
    int* flags = (int*)ws;          // [0]=bf16 [1]=stride [2]=gcount
    float* cWg   = ws + O_WG;
    float* cAtt  = ws + O_AS;
    float* cBias = ws + O_BIAS;
    float* cBih1 = ws + O_BIH1;
    float* cBhh1 = ws + O_BHH1;
    float* cBih2 = ws + O_BIH2;
    float* cBhh2 = ws + O_BHH2;
    float* cBlin = ws + O_BLIN;
    float* cP    = ws + O_P;

    float* base = ws + O_END;
    float* a_s  = base;                            // 524288
    float* a_d  = a_s + 524288;                    // 524288
    int* deg    = (int*)(a_d + 524288);            // 65536
    int* offs   = deg + 65536;                     // 65536
    int* rank   = offs + 65536;                    // E
    int* ssrc   = rank + E;                        // E
    float* gT   = (float*)(ssrc + E);              // 786432
    float* Z1   = gT + 786432;                     // 49152
    float* h2l  = Z1 + 49152;                      // 4096
    float* h1g  = h2l + 4096;                      // 12288  (12*32*32)
    float* z2g  = h1g + 12288;                     // 196608 (12*32*512)
    float* rec  = z2g + 196608;                    // 524288 (65536 * 8 dwords)
    size_t needed = (size_t)((rec + 524288) - ws) * 4;
    if (ws_size < needed) return;

    k_pre<<<256, 256, 0, stream>>>(d_in[0], (const int*)d_in[1],
                                   d_in[2], d_in[3], d_in[4], d_in[5],
                                   d_in[8], d_in[9], d_in[12], d_in[13], d_in[15],
                                   ws, deg);
    k_nfa<<<2048, 256, 0, stream>>>(d_in[0], cWg, cAtt, flags,
                                    (const int*)d_in[1], E, deg, rank,
                                    a_s, a_d, rec);
    k_scan<<<256, 256, 0, stream>>>(deg, offs, flags + 2, cWg, cAtt, cP);
    k_scatter<<<(E + 255) / 256, 256, 0, stream>>>((const int*)d_in[1], E, flags,
                                                   offs, rank, ssrc);
    k_agg<<<NTOT / 4, 256, 0, stream>>>(d_in[0], cWg, a_s, a_d, offs, deg, ssrc,
                                        cBias, flags, rec, cP, gT);
    k_z1<<<384, 256, 0, stream>>>(gT, d_in[6], cBih1, cBhh1, flags, Z1);
    k_lstm1<<<32, 64, 0, stream>>>(Z1, d_in[7], flags, h1g);
    k_wih2<<<384, 512, 0, stream>>>(h1g, d_in[10], cBih2, cBhh2, flags, z2g);
    k_lstm2<<<32, 512, 0, stream>>>(z2g, d_in[11], flags, h2l);
    k_lin<<<dim3(72, 4), 256, 0, stream>>>(h2l, d_in[14], cBlin, flags, d_out);
}

// Round 8
// 330.027 us; speedup vs baseline: 1.0997x; 1.0997x over previous
//
#include <hip/hip_runtime.h>
#include <hip/hip_bf16.h>
#include <stdint.h>

#define NTOT 65536   // B * N_NODE
#define NNODE 2048
#define CIN 12

__device__ __forceinline__ float bf2f(uint32_t u) {
    union { uint32_t i; float f; } v; v.i = u << 16; return v.f;
}
__device__ __forceinline__ uint16_t f2bf(float f) {
    union { float f; uint32_t i; } v; v.f = f;
    uint32_t x = v.i;
    uint32_t r = x + 0x7fffu + ((x >> 16) & 1u);
    return (uint16_t)(r >> 16);
}
__device__ __forceinline__ float bflo(uint32_t u) { return bf2f(u & 0xffffu); }
__device__ __forceinline__ float bfhi(uint32_t u) { return bf2f(u >> 16); }
__device__ __forceinline__ float sigmf(float x) {
    return __builtin_amdgcn_rcpf(1.0f + __expf(-x));
}
__device__ __forceinline__ float tanhfast(float x) {
    float ex = __expf(2.0f * x);
    return 1.0f - 2.0f * __builtin_amdgcn_rcpf(ex + 1.0f);
}
__device__ __forceinline__ float lrelu(float v) { return v > 0.f ? v : 0.2f * v; }

// ws float offsets (flags[0]=bf16?, flags[1]=edge stride words, flags[2]=gcount)
#define O_WG   16
#define O_AS   1168
#define O_AD   1264
#define O_BIAS 1360
#define O_BIH1 1376
#define O_BHH1 1504
#define O_BIH2 1632
#define O_BHH2 2144
#define O_BLIN 2656
#define O_P    21088   // P[h*12+k] = sum_c Wg[k,h*12+c]*att_src[h,c]  (96 floats)
#define O_END  21184

__device__ __forceinline__ void cvt(const void* s, float* d, int i, int bf) {
    d[i] = bf ? bf2f(((const uint16_t*)s)[i]) : ((const float*)s)[i];
}

// ---------- fused: dtype detect + small-tensor conv + zero ----------
__global__ void __launch_bounds__(256) k_pre(
    const void* x, const int* __restrict__ e32,
    const void* wg, const void* as_, const void* ad_, const void* bs,
    const void* b1, const void* bb1, const void* b2, const void* bb2,
    const void* bl, float* __restrict__ ws, int* __restrict__ deg) {
    int tid = threadIdx.x, lane = tid & 63;
    uint32_t u = ((const uint16_t*)x)[2 * lane];
    uint32_t ex = (u >> 7) & 0xFF;
    bool sane = (ex >= 0x60 && ex <= 0x9F) || (u == 0);
    unsigned long long bsx = __ballot(sane);
    bool hi_zero = (e32[2 * lane + 1] == 0);
    unsigned long long bz = __ballot(hi_zero);
    int bf = (__popcll(bsx) >= 52) ? 1 : 0;
    int st = (__popcll(bz) == 64) ? 2 : 1;
    if (blockIdx.x == 0 && tid == 0) {
        ((int*)ws)[0] = bf; ((int*)ws)[1] = st; ((int*)ws)[2] = 0;
    }
    deg[blockIdx.x * 256 + tid] = 0;
    int i = blockIdx.x * 256 + tid;
    if (i < 1152)  { cvt(wg,  ws + O_WG,   i, bf); return; } i -= 1152;
    if (i < 96)    { cvt(as_, ws + O_AS,   i, bf); return; } i -= 96;
    if (i < 96)    { cvt(ad_, ws + O_AD,   i, bf); return; } i -= 96;
    if (i < 12)    { cvt(bs,  ws + O_BIAS, i, bf); return; } i -= 12;
    if (i < 128)   { cvt(b1,  ws + O_BIH1, i, bf); return; } i -= 128;
    if (i < 128)   { cvt(bb1, ws + O_BHH1, i, bf); return; } i -= 128;
    if (i < 512)   { cvt(b2,  ws + O_BIH2, i, bf); return; } i -= 512;
    if (i < 512)   { cvt(bb2, ws + O_BHH2, i, bf); return; } i -= 512;
    if (i < 18432) { cvt(bl,  ws + O_BLIN, i, bf); }
}

// ---------- fused attention scores + edge histogram + packed x record ----------
// bf path writes rec[n] (32 B): [x[n][0..11] bf16 | 8 B pad] -> 2 MB footprint.
// Scores are NOT stored; k_agg recomputes a_s on the fly via folded P.
__global__ void __launch_bounds__(256) k_nfa(const void* __restrict__ xraw,
                                             const float* __restrict__ Wg,
                                             const float* __restrict__ att,
                                             const int* __restrict__ flags,
                                             const int* __restrict__ e, int E,
                                             int* __restrict__ deg, int* __restrict__ rank,
                                             float* __restrict__ a_s, float* __restrict__ a_d,
                                             float* __restrict__ rec) {
    __shared__ float sx[384];
    __shared__ float sw[1152];
    __shared__ float satt[192];
    __shared__ float sh[3072];
    int tid = threadIdx.x;
    int n0 = blockIdx.x * 32;
    int bf = flags[0];
    if (bf) {
        const uint32_t* xp = (const uint32_t*)xraw;
        uint32_t* rx = (uint32_t*)rec;
        for (int i = tid; i < 192; i += 256) {
            uint32_t u = xp[n0 * 6 + i];
            sx[2 * i] = bflo(u); sx[2 * i + 1] = bfhi(u);
            rx[(size_t)(n0 + i / 6) * 8 + i % 6] = u;  // pack x into 32B record
        }
    } else {
        const float* xp = (const float*)xraw;
        for (int i = tid; i < 384; i += 256) sx[i] = xp[n0 * 12 + i];
    }
    for (int i = tid; i < 1152; i += 256) sw[i] = Wg[i];
    if (tid < 192) satt[tid] = att[tid];
    {
        long st = flags[1];
        int chunk = (E + gridDim.x - 1) / gridDim.x;
        int ebase = blockIdx.x * chunk;
        int eend = min(ebase + chunk, E);
        for (int i = ebase + tid; i < eend; i += 256) {
            int d = e[st * (E + i)];
            rank[i] = atomicAdd(&deg[d], 1);
        }
    }
    __syncthreads();
#pragma unroll
    for (int r = 0; r < 12; r++) {
        int idx = r * 256 + tid;
        int n = idx / 96, o = idx % 96;
        float acc = 0.f;
#pragma unroll
        for (int k = 0; k < 12; k++) acc += sx[n * 12 + k] * sw[k * 96 + o];
        sh[idx] = acc;
    }
    __syncthreads();
    {
        int nl = tid >> 3, h = tid & 7;
        const float* hr = sh + nl * 96 + h * 12;
        float s = 0.f, dd = 0.f;
#pragma unroll
        for (int c = 0; c < 12; c++) {
            float v = hr[c];
            s += v * satt[h * 12 + c];
            dd += v * satt[96 + h * 12 + c];
        }
        if (!bf) a_s[n0 * 8 + tid] = s;   // f32 fallback path only
        a_d[n0 * 8 + tid] = dd;
    }
}

// ---------- scan: local exclusive scan + atomic global base (+ P fold) ----------
__global__ void k_scan(const int* __restrict__ deg, int* __restrict__ offs,
                       int* __restrict__ gcount,
                       const float* __restrict__ wg, const float* __restrict__ att,
                       float* __restrict__ P) {
    __shared__ int s[256];
    __shared__ int base;
    int t = threadIdx.x, i = blockIdx.x * 256 + t;
    if (blockIdx.x == 0 && t < 96) {     // fold Wg*att_src -> P[h*12+k]
        int h = t / 12, k = t % 12;
        float p = 0.f;
#pragma unroll
        for (int c = 0; c < 12; c++) p += wg[k * 96 + h * 12 + c] * att[h * 12 + c];
        P[h * 12 + k] = p;
    }
    int v = deg[i];
    s[t] = v; __syncthreads();
    for (int off = 1; off < 256; off <<= 1) {
        int a = (t >= off) ? s[t - off] : 0;
        __syncthreads();
        s[t] += a;
        __syncthreads();
    }
    if (t == 255) base = atomicAdd(gcount, s[255]);
    __syncthreads();
    offs[i] = base + s[t] - v;
}

__global__ void k_scatter(const int* __restrict__ e, int E, const int* __restrict__ flags,
                          const int* __restrict__ offs, const int* __restrict__ rank,
                          int* __restrict__ ssrc) {
    int i = blockIdx.x * 256 + threadIdx.x;
    if (i < E) {
        long st = flags[1];
        int s = e[st * i];
        int d = e[st * (E + i)];
        ssrc[offs[d] + rank[i]] = s;
    }
}

// ---------- GAT aggregation: 32B-record gather, on-the-fly source score ----------
__global__ void __launch_bounds__(256) k_agg(
    const void* __restrict__ xraw, const float* __restrict__ WgG,
    const float* __restrict__ a_s, const float* __restrict__ a_d,
    const int* __restrict__ offs, const int* __restrict__ deg,
    const int* __restrict__ ssrc, const float* __restrict__ bias,
    const int* __restrict__ flags, const float* __restrict__ rec,
    const float* __restrict__ P, float* __restrict__ gT) {
    __shared__ float swg[1152];
    __shared__ float sres[4][12];
    int tid = threadIdx.x, wave = tid >> 6, lane = tid & 63;
    for (int i = tid; i < 1152; i += 256) swg[i] = WgG[i];
    __syncthreads();
    int node = blockIdx.x * 4 + wave;
    int beg = offs[node], d = deg[node];
    int sub = lane >> 3, h = lane & 7;
    float adh = a_d[node * 8 + h];
    int bf = flags[0];
    float acc[12];
    float wsum = 0.f;
#pragma unroll
    for (int c = 0; c < 12; c++) acc[c] = 0.f;
    if (bf) {
        float pv[12];
        {
            const float4* pp = (const float4*)(P + h * 12);
            float4 p0 = pp[0], p1 = pp[1], p2 = pp[2];
            pv[0] = p0.x; pv[1] = p0.y; pv[2] = p0.z; pv[3] = p0.w;
            pv[4] = p1.x; pv[5] = p1.y; pv[6] = p1.z; pv[7] = p1.w;
            pv[8] = p2.x; pv[9] = p2.y; pv[10] = p2.z; pv[11] = p2.w;
        }
        // self loop from own record
        if (sub == 0) {
            const uint32_t* rp0 = (const uint32_t*)rec + (size_t)node * 8;
            uint4 xu = *(const uint4*)rp0;
            uint2 xv = *(const uint2*)(rp0 + 4);
            float xf[12];
            xf[0] = bflo(xu.x); xf[1] = bfhi(xu.x); xf[2] = bflo(xu.y); xf[3] = bfhi(xu.y);
            xf[4] = bflo(xu.z); xf[5] = bfhi(xu.z); xf[6] = bflo(xu.w); xf[7] = bfhi(xu.w);
            xf[8] = bflo(xv.x); xf[9] = bfhi(xv.x); xf[10] = bflo(xv.y); xf[11] = bfhi(xv.y);
            float asv = 0.f;
#pragma unroll
            for (int c = 0; c < 12; c++) asv += xf[c] * pv[c];
            float w = __expf(lrelu(asv + adh));
            wsum = w;
#pragma unroll
            for (int c = 0; c < 12; c++) acc[c] = w * xf[c];
        }
        if (d > 0) {
            // depth-1 software pipeline; invalid lanes masked w=0
            int k = sub;
            int s0 = ssrc[beg + min(k, d - 1)];
            const uint32_t* rp = (const uint32_t*)rec + (size_t)s0 * 8;
            uint4 xu = *(const uint4*)rp;
            uint2 xv = *(const uint2*)(rp + 4);
            for (int base = 0; base < d; base += 8, k += 8) {
                int kn = k + 8;
                int s1 = (kn < d) ? ssrc[beg + kn] : s0;
                const uint32_t* rpn = (const uint32_t*)rec + (size_t)s1 * 8;
                uint4 xu_n = *(const uint4*)rpn;
                uint2 xv_n = *(const uint2*)(rpn + 4);
                float xf[12];
                xf[0] = bflo(xu.x); xf[1] = bfhi(xu.x); xf[2] = bflo(xu.y); xf[3] = bfhi(xu.y);
                xf[4] = bflo(xu.z); xf[5] = bfhi(xu.z); xf[6] = bflo(xu.w); xf[7] = bfhi(xu.w);
                xf[8] = bflo(xv.x); xf[9] = bfhi(xv.x); xf[10] = bflo(xv.y); xf[11] = bfhi(xv.y);
                float asv = 0.f;
#pragma unroll
                for (int c = 0; c < 12; c++) asv += xf[c] * pv[c];
                float w = __expf(lrelu(asv + adh));
                if (k >= d) w = 0.f;
                wsum += w;
#pragma unroll
                for (int c = 0; c < 12; c++) acc[c] += w * xf[c];
                xu = xu_n; xv = xv_n; s0 = s1;
            }
        }
    } else {
        // legacy f32 path
        if (sub == 0) {
            float w = __expf(lrelu(a_s[node * 8 + h] + adh));
            wsum = w;
            const float4* xp = (const float4*)((const float*)xraw + node * 12);
            float4 v0 = xp[0], v1 = xp[1], v2 = xp[2];
            acc[0] = w * v0.x; acc[1] = w * v0.y; acc[2] = w * v0.z; acc[3] = w * v0.w;
            acc[4] = w * v1.x; acc[5] = w * v1.y; acc[6] = w * v1.z; acc[7] = w * v1.w;
            acc[8] = w * v2.x; acc[9] = w * v2.y; acc[10] = w * v2.z; acc[11] = w * v2.w;
        }
        for (int base = 0; base < d; base += 8) {
            int k = base + sub;
            if (k < d) {
                int s = ssrc[beg + k];
                float w = __expf(lrelu(a_s[s * 8 + h] + adh));
                wsum += w;
                const float4* xp = (const float4*)((const float*)xraw + s * 12);
                float4 v0 = xp[0], v1 = xp[1], v2 = xp[2];
                acc[0] += w * v0.x; acc[1] += w * v0.y; acc[2] += w * v0.z; acc[3] += w * v0.w;
                acc[4] += w * v1.x; acc[5] += w * v1.y; acc[6] += w * v1.z; acc[7] += w * v1.w;
                acc[8] += w * v2.x; acc[9] += w * v2.y; acc[10] += w * v2.z; acc[11] += w * v2.w;
            }
        }
    }
#pragma unroll
    for (int off = 8; off <= 32; off <<= 1) {
        wsum += __shfl_xor(wsum, off, 64);
#pragma unroll
        for (int c = 0; c < 12; c++) acc[c] += __shfl_xor(acc[c], off, 64);
    }
    float invw = 1.f / wsum;
#pragma unroll
    for (int c = 0; c < 12; c++) acc[c] *= invw;
    float p0 = 0.f, p1 = 0.f;
    const float* wcol = swg + h * 12;
#pragma unroll
    for (int k = 0; k < 12; k++) {
        float a = acc[k];
        p0 += a * wcol[k * 96 + sub];
        p1 += a * wcol[k * 96 + sub + 4];
    }
#pragma unroll
    for (int off = 1; off <= 4; off <<= 1) {
        p0 += __shfl_xor(p0, off, 64);
        p1 += __shfl_xor(p1, off, 64);
    }
    if (h == 0) {
        sres[wave][sub] = p0;
        if (sub >= 4) sres[wave][sub + 4] = p1;
    }
    __syncthreads();
    if (tid < 48) {
        int no = tid / 12, c = tid % 12;
        gT[c * NTOT + blockIdx.x * 4 + no] = sres[no][c] * 0.125f + bias[c];
    }
}

// ---------- Z1: one (t, batch) per block -> 384 blocks (96 used 37% of CUs) ----------
__global__ void __launch_bounds__(256) k_z1(const float* __restrict__ gT,
                                            const void* __restrict__ Wraw,
                                            const float* __restrict__ b1,
                                            const float* __restrict__ b2,
                                            const int* __restrict__ flags,
                                            float* __restrict__ Z1) {
    int t = blockIdx.x >> 5, b = blockIdx.x & 31;
    __shared__ float sv[2048];
    __shared__ float zp[2][128];
    int tid = threadIdx.x;
    for (int v = tid; v < 2048; v += 256) sv[v] = gT[t * NTOT + b * NNODE + v];
    __syncthreads();
    int row = tid & 127, half = tid >> 7;
    float a = 0.f;
    int hbase = half * 1024;
    if (flags[0]) {
        const uint4* wp = (const uint4*)((const uint16_t*)Wraw + row * 2048 + hbase);
        for (int k = 0; k < 128; k++) {
            uint4 u = wp[k];
            float w0 = bflo(u.x), w1 = bfhi(u.x), w2 = bflo(u.y), w3 = bfhi(u.y);
            float w4 = bflo(u.z), w5 = bfhi(u.z), w6 = bflo(u.w), w7 = bfhi(u.w);
            float4 A = *(const float4*)&sv[hbase + 8 * k];
            float4 B = *(const float4*)&sv[hbase + 8 * k + 4];
            a += w0 * A.x + w1 * A.y + w2 * A.z + w3 * A.w
               + w4 * B.x + w5 * B.y + w6 * B.z + w7 * B.w;
        }
    } else {
        const float4* wp = (const float4*)((const float*)Wraw + row * 2048 + hbase);
        for (int k = 0; k < 256; k++) {
            float4 w = wp[k];
            float4 A = *(const float4*)&sv[hbase + 4 * k];
            a += w.x * A.x + w.y * A.y + w.z * A.z + w.w * A.w;
        }
    }
    zp[half][row] = a;
    __syncthreads();
    if (tid < 128)
        Z1[t * 4096 + b * 128 + tid] = zp[0][tid] + zp[1][tid] + b1[tid] + b2[tid];
}

// ---------- LSTM1: one block (64 thr) per batch, fully unrolled ----------
__global__ void __launch_bounds__(64) k_lstm1(
    const float* __restrict__ Z1, const void* __restrict__ Whh1r,
    const int* __restrict__ flags, float* __restrict__ h1g) {
    int b = blockIdx.x, l = threadIdx.x;
    __shared__ __align__(16) float hb1[32];
    int bf = flags[0];
    float wA[32], wB[32];
    if (bf) {
        const uint32_t* w1 = (const uint32_t*)Whh1r;
#pragma unroll
        for (int k = 0; k < 16; k++) {
            uint32_t u = w1[l * 16 + k];
            wA[2 * k] = bflo(u); wA[2 * k + 1] = bfhi(u);
            uint32_t v = w1[(l + 64) * 16 + k];
            wB[2 * k] = bflo(v); wB[2 * k + 1] = bfhi(v);
        }
    } else {
        const float* w1 = (const float*)Whh1r;
#pragma unroll
        for (int k = 0; k < 32; k++) {
            wA[k] = w1[l * 32 + k];
            wB[k] = w1[(l + 64) * 32 + k];
        }
    }
    float za[12], zg[12];
#pragma unroll
    for (int t = 0; t < 12; t++) {
        za[t] = Z1[t * 4096 + b * 128 + l];
        zg[t] = Z1[t * 4096 + b * 128 + 64 + l];
    }
    if (l < 32) hb1[l] = 0.f;
    __builtin_amdgcn_wave_barrier();
    float c = 0.f;
#pragma unroll
    for (int t = 0; t < 12; t++) {
        float d0 = za[t], d1 = zg[t];
#pragma unroll
        for (int k = 0; k < 8; k++) {
            float4 h4 = *(const float4*)&hb1[4 * k];
            d0 += wA[4*k]*h4.x + wA[4*k+1]*h4.y + wA[4*k+2]*h4.z + wA[4*k+3]*h4.w;
            d1 += wB[4*k]*h4.x + wB[4*k+1]*h4.y + wB[4*k+2]*h4.z + wB[4*k+3]*h4.w;
        }
        float e0 = __shfl_xor(d0, 32, 64);
        float e1 = __shfl_xor(d1, 32, 64);
        if (l < 32) {
            c = sigmf(e0) * c + sigmf(d0) * tanhfast(d1);
            float h = sigmf(e1) * tanhfast(c);
            hb1[l] = h;
            h1g[t * 1024 + b * 32 + l] = h;
        }
        __builtin_amdgcn_wave_barrier();
    }
}

// ---------- Wih2 projection: t-parallel, one row per thread ----------
__global__ void __launch_bounds__(512) k_wih2(
    const float* __restrict__ h1g, const void* __restrict__ Wih2r,
    const float* __restrict__ b2i, const float* __restrict__ b2h,
    const int* __restrict__ flags, float* __restrict__ z2g) {
    int tb = blockIdx.x;              // t*32 + b
    int t = tb >> 5, b = tb & 31;
    int r = threadIdx.x;              // 0..511
    __shared__ __align__(16) float h[32];
    if (r < 32) h[r] = h1g[t * 1024 + b * 32 + r];
    __syncthreads();
    float z = b2i[r] + b2h[r];
    const float4* hp = (const float4*)h;
    if (flags[0]) {
        const uint4* wp = (const uint4*)((const uint16_t*)Wih2r + r * 32);
#pragma unroll
        for (int k = 0; k < 4; k++) {
            uint4 u = wp[k];
            float4 h0 = hp[2 * k], h1 = hp[2 * k + 1];
            z += bflo(u.x)*h0.x + bfhi(u.x)*h0.y + bflo(u.y)*h0.z + bfhi(u.y)*h0.w
               + bflo(u.z)*h1.x + bfhi(u.z)*h1.y + bflo(u.w)*h1.z + bfhi(u.w)*h1.w;
        }
    } else {
        const float4* wp = (const float4*)((const float*)Wih2r + r * 32);
#pragma unroll
        for (int k = 0; k < 8; k++) {
            float4 w = wp[k];
            float4 h4 = hp[k];
            z += w.x*h4.x + w.y*h4.y + w.z*h4.z + w.w*h4.w;
        }
    }
    z2g[t * 16384 + b * 512 + r] = z;
}

// ---------- LSTM2: one block (512 thr) per batch, f32-pinned weights ----------
__global__ void __launch_bounds__(512, 1) k_lstm2(
    const float* __restrict__ z2g, const void* __restrict__ Whh2r,
    const int* __restrict__ flags, float* __restrict__ h2l) {
    int b = blockIdx.x, tid = threadIdx.x;
    __shared__ __align__(16) float hb[2][128];
    int bf = flags[0];
    int lane = tid & 63, wv = tid >> 6;
    int kh = lane >> 5;
    int gp = (lane >> 4) & 1;
    int e = wv * 16 + (lane & 15);
    int rA = gp * 256 + e;
    int rB = gp * 256 + 128 + e;

    float wA[64], wB[64];
    if (bf) {
        const uint16_t* W2 = (const uint16_t*)Whh2r;
        const uint4* pA = (const uint4*)(W2 + rA * 128 + kh * 64);
        const uint4* pB = (const uint4*)(W2 + rB * 128 + kh * 64);
#pragma unroll
        for (int k = 0; k < 8; k++) {
            uint4 ua = pA[k], ub = pB[k];
            wA[8*k+0] = bflo(ua.x); wA[8*k+1] = bfhi(ua.x);
            wA[8*k+2] = bflo(ua.y); wA[8*k+3] = bfhi(ua.y);
            wA[8*k+4] = bflo(ua.z); wA[8*k+5] = bfhi(ua.z);
            wA[8*k+6] = bflo(ua.w); wA[8*k+7] = bfhi(ua.w);
            wB[8*k+0] = bflo(ub.x); wB[8*k+1] = bfhi(ub.x);
            wB[8*k+2] = bflo(ub.y); wB[8*k+3] = bfhi(ub.y);
            wB[8*k+4] = bflo(ub.z); wB[8*k+5] = bfhi(ub.z);
            wB[8*k+6] = bflo(ub.w); wB[8*k+7] = bfhi(ub.w);
        }
    } else {
        const float4* pA = (const float4*)((const float*)Whh2r + rA * 128 + kh * 64);
        const float4* pB = (const float4*)((const float*)Whh2r + rB * 128 + kh * 64);
#pragma unroll
        for (int k = 0; k < 16; k++) {
            float4 a = pA[k], c = pB[k];
            wA[4*k+0] = a.x; wA[4*k+1] = a.y; wA[4*k+2] = a.z; wA[4*k+3] = a.w;
            wB[4*k+0] = c.x; wB[4*k+1] = c.y; wB[4*k+2] = c.z; wB[4*k+3] = c.w;
        }
    }
    if (tid < 128) hb[0][tid] = 0.f;
    const float* zb = z2g + b * 512;
    float zA = 0.f, zB = 0.f;
    if (kh == 0) { zA = zb[rA]; zB = zb[rB]; }
    float c2 = 0.f;
    __syncthreads();
#pragma unroll 1
    for (int t = 0; t < 12; t++) {
        float nA = 0.f, nB = 0.f;
        if (t < 11 && kh == 0) {       // prefetch next step's z (L2-hit)
            nA = zb[(t + 1) * 16384 + rA];
            nB = zb[(t + 1) * 16384 + rB];
        }
        const float4* hp = (const float4*)&hb[t & 1][kh * 64];
        float pA = zA, pB = zB;
#pragma unroll
        for (int k = 0; k < 16; k++) {
            float4 h4 = hp[k];
            pA += wA[4*k]*h4.x + wA[4*k+1]*h4.y + wA[4*k+2]*h4.z + wA[4*k+3]*h4.w;
            pB += wB[4*k]*h4.x + wB[4*k+1]*h4.y + wB[4*k+2]*h4.z + wB[4*k+3]*h4.w;
        }
        float sA = pA + __shfl_xor(pA, 32, 64);
        float sB = pB + __shfl_xor(pB, 32, 64);
        float zg_ = __shfl_xor(sA, 16, 64);
        float zo_ = __shfl_xor(sB, 16, 64);
        if (gp == 0) {
            c2 = sigmf(sB) * c2 + sigmf(sA) * tanhfast(zg_);
            float hh = sigmf(zo_) * tanhfast(c2);
            if (kh == 0) {
                hb[(t & 1) ^ 1][e] = hh;
                if (t == 11) h2l[b * 128 + e] = hh;
            }
        }
        __syncthreads();
        zA = nA; zB = nB;
    }
}

// ---------- final linear (dual-path W) ----------
__global__ void __launch_bounds__(256) k_lin(const float* __restrict__ h2l,
                                             const void* __restrict__ Wraw,
                                             const float* __restrict__ bl,
                                             const int* __restrict__ flags,
                                             void* __restrict__ outv) {
    __shared__ float hl[8 * 128];
    int bg = blockIdx.y;
    for (int i = threadIdx.x; i < 1024; i += 256) hl[i] = h2l[bg * 1024 + i];
    __syncthreads();
    int o = blockIdx.x * 256 + threadIdx.x;
    float bb = bl[o];
    float acc[8];
#pragma unroll
    for (int b = 0; b < 8; b++) acc[b] = bb;
    int bf = flags[0];
    if (bf) {
        const uint4* wp = (const uint4*)((const uint16_t*)Wraw + o * 128);
        for (int k = 0; k < 16; k++) {
            uint4 u = wp[k];
            float w0 = bflo(u.x), w1 = bfhi(u.x), w2 = bflo(u.y), w3 = bfhi(u.y);
            float w4 = bflo(u.z), w5 = bfhi(u.z), w6 = bflo(u.w), w7 = bfhi(u.w);
#pragma unroll
            for (int b = 0; b < 8; b++) {
                const float* h8 = hl + b * 128 + k * 8;
                acc[b] += w0 * h8[0] + w1 * h8[1] + w2 * h8[2] + w3 * h8[3]
                        + w4 * h8[4] + w5 * h8[5] + w6 * h8[6] + w7 * h8[7];
            }
        }
    } else {
        const float4* wp = (const float4*)((const float*)Wraw + o * 128);
        for (int k = 0; k < 32; k++) {
            float4 w = wp[k];
#pragma unroll
            for (int b = 0; b < 8; b++) {
                const float* h4 = hl + b * 128 + k * 4;
                acc[b] += w.x * h4[0] + w.y * h4[1] + w.z * h4[2] + w.w * h4[3];
            }
        }
    }
    if (bf) {
        uint16_t* out = (uint16_t*)outv;
#pragma unroll
        for (int b = 0; b < 8; b++) out[(bg * 8 + b) * 18432 + o] = f2bf(acc[b]);
    } else {
        float* out = (float*)outv;
#pragma unroll
        for (int b = 0; b < 8; b++) out[(bg * 8 + b) * 18432 + o] = acc[b];
    }
}

extern "C" void kernel_launch(void* const* d_in, const int* in_sizes, int n_in,
                              void* d_out, int out_size, void* d_ws, size_t ws_size,
                              hipStream_t stream) {
    int E = in_sizes[1] / 2;

    float* ws = (float*)d_ws;
    int* flags = (int*)ws;          // [0]=bf16 [1]=stride [2]=gcount
    float* cWg   = ws + O_WG;
    float* cAtt  = ws + O_AS;
    float* cBias = ws + O_BIAS;
    float* cBih1 = ws + O_BIH1;
    float* cBhh1 = ws + O_BHH1;
    float* cBih2 = ws + O_BIH2;
    float* cBhh2 = ws + O_BHH2;
    float* cBlin = ws + O_BLIN;
    float* cP    = ws + O_P;

    float* base = ws + O_END;
    float* a_s  = base;                            // 524288
    float* a_d  = a_s + 524288;                    // 524288
    int* deg    = (int*)(a_d + 524288);            // 65536
    int* offs   = deg + 65536;                     // 65536
    int* rank   = offs + 65536;                    // E
    int* ssrc   = rank + E;                        // E
    float* gT   = (float*)(ssrc + E);              // 786432
    float* Z1   = gT + 786432;                     // 49152
    float* h2l  = Z1 + 49152;                      // 4096
    float* h1g  = h2l + 4096;                      // 12288  (12*32*32)
    float* z2g  = h1g + 12288;                     // 196608 (12*32*512)
    float* rec  = z2g + 196608;                    // 524288 (65536 * 8 dwords)
    size_t needed = (size_t)((rec + 524288) - ws) * 4;
    if (ws_size < needed) return;

    k_pre<<<256, 256, 0, stream>>>(d_in[0], (const int*)d_in[1],
                                   d_in[2], d_in[3], d_in[4], d_in[5],
                                   d_in[8], d_in[9], d_in[12], d_in[13], d_in[15],
                                   ws, deg);
    k_nfa<<<2048, 256, 0, stream>>>(d_in[0], cWg, cAtt, flags,
                                    (const int*)d_in[1], E, deg, rank,
                                    a_s, a_d, rec);
    k_scan<<<256, 256, 0, stream>>>(deg, offs, flags + 2, cWg, cAtt, cP);
    k_scatter<<<(E + 255) / 256, 256, 0, stream>>>((const int*)d_in[1], E, flags,
                                                   offs, rank, ssrc);
    k_agg<<<NTOT / 4, 256, 0, stream>>>(d_in[0], cWg, a_s, a_d, offs, deg, ssrc,
                                        cBias, flags, rec, cP, gT);
    k_z1<<<384, 256, 0, stream>>>(gT, d_in[6], cBih1, cBhh1, flags, Z1);
    k_lstm1<<<32, 64, 0, stream>>>(Z1, d_in[7], flags, h1g);
    k_wih2<<<384, 512, 0, stream>>>(h1g, d_in[10], cBih2, cBhh2, flags, z2g);
    k_lstm2<<<32, 512, 0, stream>>>(z2g, d_in[11], flags, h2l);
    k_lin<<<dim3(72, 4), 256, 0, stream>>>(h2l, d_in[14], cBlin, flags, d_out);
}

// Round 9
// 309.175 us; speedup vs baseline: 1.1739x; 1.0674x over previous
//
#include <hip/hip_runtime.h>
#include <hip/hip_bf16.h>
#include <stdint.h>

#define NTOT 65536   // B * N_NODE
#define NNODE 2048
#define CIN 12

__device__ __forceinline__ float bf2f(uint32_t u) {
    union { uint32_t i; float f; } v; v.i = u << 16; return v.f;
}
__device__ __forceinline__ uint16_t f2bf(float f) {
    union { float f; uint32_t i; } v; v.f = f;
    uint32_t x = v.i;
    uint32_t r = x + 0x7fffu + ((x >> 16) & 1u);
    return (uint16_t)(r >> 16);
}
__device__ __forceinline__ float bflo(uint32_t u) { return bf2f(u & 0xffffu); }
__device__ __forceinline__ float bfhi(uint32_t u) { return bf2f(u >> 16); }
__device__ __forceinline__ float sigmf(float x) {
    return __builtin_amdgcn_rcpf(1.0f + __expf(-x));
}
__device__ __forceinline__ float tanhfast(float x) {
    float ex = __expf(2.0f * x);
    return 1.0f - 2.0f * __builtin_amdgcn_rcpf(ex + 1.0f);
}
__device__ __forceinline__ float lrelu(float v) { return v > 0.f ? v : 0.2f * v; }

// ws float offsets (flags[0]=bf16?, flags[1]=edge stride words, flags[2]=gcount)
#define O_WG   16
#define O_AS   1168
#define O_AD   1264
#define O_BIAS 1360
#define O_BIH1 1376
#define O_BHH1 1504
#define O_BIH2 1632
#define O_BHH2 2144
#define O_BLIN 2656
#define O_P    21088   // P[h*12+k] = sum_c Wg[k,h*12+c]*att_src[h,c]  (96 floats)
#define O_END  21184

__device__ __forceinline__ void cvt(const void* s, float* d, int i, int bf) {
    d[i] = bf ? bf2f(((const uint16_t*)s)[i]) : ((const float*)s)[i];
}

// ---------- fused: dtype detect + small-tensor conv + zero ----------
__global__ void __launch_bounds__(256) k_pre(
    const void* x, const int* __restrict__ e32,
    const void* wg, const void* as_, const void* ad_, const void* bs,
    const void* b1, const void* bb1, const void* b2, const void* bb2,
    const void* bl, float* __restrict__ ws, int* __restrict__ deg) {
    int tid = threadIdx.x, lane = tid & 63;
    uint32_t u = ((const uint16_t*)x)[2 * lane];
    uint32_t ex = (u >> 7) & 0xFF;
    bool sane = (ex >= 0x60 && ex <= 0x9F) || (u == 0);
    unsigned long long bsx = __ballot(sane);
    bool hi_zero = (e32[2 * lane + 1] == 0);
    unsigned long long bz = __ballot(hi_zero);
    int bf = (__popcll(bsx) >= 52) ? 1 : 0;
    int st = (__popcll(bz) == 64) ? 2 : 1;
    if (blockIdx.x == 0 && tid == 0) {
        ((int*)ws)[0] = bf; ((int*)ws)[1] = st; ((int*)ws)[2] = 0;
    }
    deg[blockIdx.x * 256 + tid] = 0;
    int i = blockIdx.x * 256 + tid;
    if (i < 1152)  { cvt(wg,  ws + O_WG,   i, bf); return; } i -= 1152;
    if (i < 96)    { cvt(as_, ws + O_AS,   i, bf); return; } i -= 96;
    if (i < 96)    { cvt(ad_, ws + O_AD,   i, bf); return; } i -= 96;
    if (i < 12)    { cvt(bs,  ws + O_BIAS, i, bf); return; } i -= 12;
    if (i < 128)   { cvt(b1,  ws + O_BIH1, i, bf); return; } i -= 128;
    if (i < 128)   { cvt(bb1, ws + O_BHH1, i, bf); return; } i -= 128;
    if (i < 512)   { cvt(b2,  ws + O_BIH2, i, bf); return; } i -= 512;
    if (i < 512)   { cvt(bb2, ws + O_BHH2, i, bf); return; } i -= 512;
    if (i < 18432) { cvt(bl,  ws + O_BLIN, i, bf); }
}

// ---------- fused attention scores + edge histogram + packed x record ----------
// bf path writes rec[n] (32 B): [x[n][0..11] bf16 | 8 B pad] -> 2 MB footprint.
// Scores are NOT stored; k_agg recomputes a_s on the fly via folded P.
__global__ void __launch_bounds__(256) k_nfa(const void* __restrict__ xraw,
                                             const float* __restrict__ Wg,
                                             const float* __restrict__ att,
                                             const int* __restrict__ flags,
                                             const int* __restrict__ e, int E,
                                             int* __restrict__ deg, int* __restrict__ rank,
                                             float* __restrict__ a_s, float* __restrict__ a_d,
                                             float* __restrict__ rec) {
    __shared__ float sx[384];
    __shared__ float sw[1152];
    __shared__ float satt[192];
    __shared__ float sh[3072];
    int tid = threadIdx.x;
    int n0 = blockIdx.x * 32;
    int bf = flags[0];
    if (bf) {
        const uint32_t* xp = (const uint32_t*)xraw;
        uint32_t* rx = (uint32_t*)rec;
        for (int i = tid; i < 192; i += 256) {
            uint32_t u = xp[n0 * 6 + i];
            sx[2 * i] = bflo(u); sx[2 * i + 1] = bfhi(u);
            rx[(size_t)(n0 + i / 6) * 8 + i % 6] = u;  // pack x into 32B record
        }
    } else {
        const float* xp = (const float*)xraw;
        for (int i = tid; i < 384; i += 256) sx[i] = xp[n0 * 12 + i];
    }
    for (int i = tid; i < 1152; i += 256) sw[i] = Wg[i];
    if (tid < 192) satt[tid] = att[tid];
    {
        long st = flags[1];
        int chunk = (E + gridDim.x - 1) / gridDim.x;
        int ebase = blockIdx.x * chunk;
        int eend = min(ebase + chunk, E);
        for (int i = ebase + tid; i < eend; i += 256) {
            int d = e[st * (E + i)];
            rank[i] = atomicAdd(&deg[d], 1);
        }
    }
    __syncthreads();
#pragma unroll
    for (int r = 0; r < 12; r++) {
        int idx = r * 256 + tid;
        int n = idx / 96, o = idx % 96;
        float acc = 0.f;
#pragma unroll
        for (int k = 0; k < 12; k++) acc += sx[n * 12 + k] * sw[k * 96 + o];
        sh[idx] = acc;
    }
    __syncthreads();
    {
        int nl = tid >> 3, h = tid & 7;
        const float* hr = sh + nl * 96 + h * 12;
        float s = 0.f, dd = 0.f;
#pragma unroll
        for (int c = 0; c < 12; c++) {
            float v = hr[c];
            s += v * satt[h * 12 + c];
            dd += v * satt[96 + h * 12 + c];
        }
        if (!bf) a_s[n0 * 8 + tid] = s;   // f32 fallback path only
        a_d[n0 * 8 + tid] = dd;
    }
}

// ---------- scan: local exclusive scan + atomic global base (+ P fold) ----------
__global__ void k_scan(const int* __restrict__ deg, int* __restrict__ offs,
                       int* __restrict__ gcount,
                       const float* __restrict__ wg, const float* __restrict__ att,
                       float* __restrict__ P) {
    __shared__ int s[256];
    __shared__ int base;
    int t = threadIdx.x, i = blockIdx.x * 256 + t;
    if (blockIdx.x == 0 && t < 96) {     // fold Wg*att_src -> P[h*12+k]
        int h = t / 12, k = t % 12;
        float p = 0.f;
#pragma unroll
        for (int c = 0; c < 12; c++) p += wg[k * 96 + h * 12 + c] * att[h * 12 + c];
        P[h * 12 + k] = p;
    }
    int v = deg[i];
    s[t] = v; __syncthreads();
    for (int off = 1; off < 256; off <<= 1) {
        int a = (t >= off) ? s[t - off] : 0;
        __syncthreads();
        s[t] += a;
        __syncthreads();
    }
    if (t == 255) base = atomicAdd(gcount, s[255]);
    __syncthreads();
    offs[i] = base + s[t] - v;
}

__global__ void k_scatter(const int* __restrict__ e, int E, const int* __restrict__ flags,
                          const int* __restrict__ offs, const int* __restrict__ rank,
                          int* __restrict__ ssrc) {
    int i = blockIdx.x * 256 + threadIdx.x;
    if (i < E) {
        long st = flags[1];
        int s = e[st * i];
        int d = e[st * (E + i)];
        ssrc[offs[d] + rank[i]] = s;
    }
}

// ---------- GAT aggregation: 32B-record gather, on-the-fly source score ----------
__global__ void __launch_bounds__(256) k_agg(
    const void* __restrict__ xraw, const float* __restrict__ WgG,
    const float* __restrict__ a_s, const float* __restrict__ a_d,
    const int* __restrict__ offs, const int* __restrict__ deg,
    const int* __restrict__ ssrc, const float* __restrict__ bias,
    const int* __restrict__ flags, const float* __restrict__ rec,
    const float* __restrict__ P, float* __restrict__ gT) {
    __shared__ float swg[1152];
    __shared__ float sres[4][12];
    int tid = threadIdx.x, wave = tid >> 6, lane = tid & 63;
    for (int i = tid; i < 1152; i += 256) swg[i] = WgG[i];
    __syncthreads();
    int node = blockIdx.x * 4 + wave;
    int beg = offs[node], d = deg[node];
    int sub = lane >> 3, h = lane & 7;
    float adh = a_d[node * 8 + h];
    int bf = flags[0];
    float acc[12];
    float wsum = 0.f;
#pragma unroll
    for (int c = 0; c < 12; c++) acc[c] = 0.f;
    if (bf) {
        float pv[12];
        {
            const float4* pp = (const float4*)(P + h * 12);
            float4 p0 = pp[0], p1 = pp[1], p2 = pp[2];
            pv[0] = p0.x; pv[1] = p0.y; pv[2] = p0.z; pv[3] = p0.w;
            pv[4] = p1.x; pv[5] = p1.y; pv[6] = p1.z; pv[7] = p1.w;
            pv[8] = p2.x; pv[9] = p2.y; pv[10] = p2.z; pv[11] = p2.w;
        }
        // self loop from own record
        if (sub == 0) {
            const uint32_t* rp0 = (const uint32_t*)rec + (size_t)node * 8;
            uint4 xu = *(const uint4*)rp0;
            uint2 xv = *(const uint2*)(rp0 + 4);
            float xf[12];
            xf[0] = bflo(xu.x); xf[1] = bfhi(xu.x); xf[2] = bflo(xu.y); xf[3] = bfhi(xu.y);
            xf[4] = bflo(xu.z); xf[5] = bfhi(xu.z); xf[6] = bflo(xu.w); xf[7] = bfhi(xu.w);
            xf[8] = bflo(xv.x); xf[9] = bfhi(xv.x); xf[10] = bflo(xv.y); xf[11] = bfhi(xv.y);
            float asv = 0.f;
#pragma unroll
            for (int c = 0; c < 12; c++) asv += xf[c] * pv[c];
            float w = __expf(lrelu(asv + adh));
            wsum = w;
#pragma unroll
            for (int c = 0; c < 12; c++) acc[c] = w * xf[c];
        }
        if (d > 0) {
            // depth-1 software pipeline; invalid lanes masked w=0
            int k = sub;
            int s0 = ssrc[beg + min(k, d - 1)];
            const uint32_t* rp = (const uint32_t*)rec + (size_t)s0 * 8;
            uint4 xu = *(const uint4*)rp;
            uint2 xv = *(const uint2*)(rp + 4);
            for (int base = 0; base < d; base += 8, k += 8) {
                int kn = k + 8;
                int s1 = (kn < d) ? ssrc[beg + kn] : s0;
                const uint32_t* rpn = (const uint32_t*)rec + (size_t)s1 * 8;
                uint4 xu_n = *(const uint4*)rpn;
                uint2 xv_n = *(const uint2*)(rpn + 4);
                float xf[12];
                xf[0] = bflo(xu.x); xf[1] = bfhi(xu.x); xf[2] = bflo(xu.y); xf[3] = bfhi(xu.y);
                xf[4] = bflo(xu.z); xf[5] = bfhi(xu.z); xf[6] = bflo(xu.w); xf[7] = bfhi(xu.w);
                xf[8] = bflo(xv.x); xf[9] = bfhi(xv.x); xf[10] = bflo(xv.y); xf[11] = bfhi(xv.y);
                float asv = 0.f;
#pragma unroll
                for (int c = 0; c < 12; c++) asv += xf[c] * pv[c];
                float w = __expf(lrelu(asv + adh));
                if (k >= d) w = 0.f;
                wsum += w;
#pragma unroll
                for (int c = 0; c < 12; c++) acc[c] += w * xf[c];
                xu = xu_n; xv = xv_n; s0 = s1;
            }
        }
    } else {
        // legacy f32 path
        if (sub == 0) {
            float w = __expf(lrelu(a_s[node * 8 + h] + adh));
            wsum = w;
            const float4* xp = (const float4*)((const float*)xraw + node * 12);
            float4 v0 = xp[0], v1 = xp[1], v2 = xp[2];
            acc[0] = w * v0.x; acc[1] = w * v0.y; acc[2] = w * v0.z; acc[3] = w * v0.w;
            acc[4] = w * v1.x; acc[5] = w * v1.y; acc[6] = w * v1.z; acc[7] = w * v1.w;
            acc[8] = w * v2.x; acc[9] = w * v2.y; acc[10] = w * v2.z; acc[11] = w * v2.w;
        }
        for (int base = 0; base < d; base += 8) {
            int k = base + sub;
            if (k < d) {
                int s = ssrc[beg + k];
                float w = __expf(lrelu(a_s[s * 8 + h] + adh));
                wsum += w;
                const float4* xp = (const float4*)((const float*)xraw + s * 12);
                float4 v0 = xp[0], v1 = xp[1], v2 = xp[2];
                acc[0] += w * v0.x; acc[1] += w * v0.y; acc[2] += w * v0.z; acc[3] += w * v0.w;
                acc[4] += w * v1.x; acc[5] += w * v1.y; acc[6] += w * v1.z; acc[7] += w * v1.w;
                acc[8] += w * v2.x; acc[9] += w * v2.y; acc[10] += w * v2.z; acc[11] += w * v2.w;
            }
        }
    }
#pragma unroll
    for (int off = 8; off <= 32; off <<= 1) {
        wsum += __shfl_xor(wsum, off, 64);
#pragma unroll
        for (int c = 0; c < 12; c++) acc[c] += __shfl_xor(acc[c], off, 64);
    }
    float invw = 1.f / wsum;
#pragma unroll
    for (int c = 0; c < 12; c++) acc[c] *= invw;
    float p0 = 0.f, p1 = 0.f;
    const float* wcol = swg + h * 12;
#pragma unroll
    for (int k = 0; k < 12; k++) {
        float a = acc[k];
        p0 += a * wcol[k * 96 + sub];
        p1 += a * wcol[k * 96 + sub + 4];
    }
#pragma unroll
    for (int off = 1; off <= 4; off <<= 1) {
        p0 += __shfl_xor(p0, off, 64);
        p1 += __shfl_xor(p1, off, 64);
    }
    if (h == 0) {
        sres[wave][sub] = p0;
        if (sub >= 4) sres[wave][sub + 4] = p1;
    }
    __syncthreads();
    if (tid < 48) {
        int no = tid / 12, c = tid % 12;
        gT[c * NTOT + blockIdx.x * 4 + no] = sres[no][c] * 0.125f + bias[c];
    }
}

// ---------- Z1: 4 batches per block, weight loads amortized (96 blocks) ----------
// NOTE: measured-good form. The 384-block single-batch variant quadruples W
// traffic (48->192 MB) and cost +20 us (R8) -- 4-batch amortization is load-bearing.
__global__ void __launch_bounds__(256) k_z1(const float* __restrict__ gT,
                                            const void* __restrict__ Wraw,
                                            const float* __restrict__ b1,
                                            const float* __restrict__ b2,
                                            const int* __restrict__ flags,
                                            float* __restrict__ Z1) {
    int t = blockIdx.x >> 3, bg = (blockIdx.x & 7) * 4;
    __shared__ float sv[4][2048];
    __shared__ float zp[2][4][128];
    int tid = threadIdx.x;
#pragma unroll
    for (int q = 0; q < 4; q++)
        for (int v = tid; v < 2048; v += 256) sv[q][v] = gT[t * NTOT + (bg + q) * NNODE + v];
    __syncthreads();
    int row = tid & 127, half = tid >> 7;
    float a0 = 0.f, a1 = 0.f, a2 = 0.f, a3 = 0.f;
    int hbase = half * 1024;
    if (flags[0]) {
        const uint4* wp = (const uint4*)((const uint16_t*)Wraw + row * 2048 + hbase);
        for (int k = 0; k < 128; k++) {
            uint4 u = wp[k];
            float w0 = bflo(u.x), w1 = bfhi(u.x), w2 = bflo(u.y), w3 = bfhi(u.y);
            float w4 = bflo(u.z), w5 = bfhi(u.z), w6 = bflo(u.w), w7 = bfhi(u.w);
#pragma unroll
            for (int q = 0; q < 4; q++) {
                float4 A = *(const float4*)&sv[q][hbase + 8 * k];
                float4 B = *(const float4*)&sv[q][hbase + 8 * k + 4];
                float r = w0 * A.x + w1 * A.y + w2 * A.z + w3 * A.w
                        + w4 * B.x + w5 * B.y + w6 * B.z + w7 * B.w;
                if (q == 0) a0 += r; else if (q == 1) a1 += r;
                else if (q == 2) a2 += r; else a3 += r;
            }
        }
    } else {
        const float4* wp = (const float4*)((const float*)Wraw + row * 2048 + hbase);
        for (int k = 0; k < 256; k++) {
            float4 w = wp[k];
#pragma unroll
            for (int q = 0; q < 4; q++) {
                float4 A = *(const float4*)&sv[q][hbase + 4 * k];
                float r = w.x * A.x + w.y * A.y + w.z * A.z + w.w * A.w;
                if (q == 0) a0 += r; else if (q == 1) a1 += r;
                else if (q == 2) a2 += r; else a3 += r;
            }
        }
    }
    zp[half][0][row] = a0; zp[half][1][row] = a1;
    zp[half][2][row] = a2; zp[half][3][row] = a3;
    __syncthreads();
    if (tid < 128) {
        float bb = b1[tid] + b2[tid];
#pragma unroll
        for (int q = 0; q < 4; q++)
            Z1[t * 4096 + (bg + q) * 128 + tid] = zp[0][q][tid] + zp[1][q][tid] + bb;
    }
}

// ---------- LSTM1: one block (64 thr) per batch, fully unrolled ----------
__global__ void __launch_bounds__(64) k_lstm1(
    const float* __restrict__ Z1, const void* __restrict__ Whh1r,
    const int* __restrict__ flags, float* __restrict__ h1g) {
    int b = blockIdx.x, l = threadIdx.x;
    __shared__ __align__(16) float hb1[32];
    int bf = flags[0];
    float wA[32], wB[32];
    if (bf) {
        const uint32_t* w1 = (const uint32_t*)Whh1r;
#pragma unroll
        for (int k = 0; k < 16; k++) {
            uint32_t u = w1[l * 16 + k];
            wA[2 * k] = bflo(u); wA[2 * k + 1] = bfhi(u);
            uint32_t v = w1[(l + 64) * 16 + k];
            wB[2 * k] = bflo(v); wB[2 * k + 1] = bfhi(v);
        }
    } else {
        const float* w1 = (const float*)Whh1r;
#pragma unroll
        for (int k = 0; k < 32; k++) {
            wA[k] = w1[l * 32 + k];
            wB[k] = w1[(l + 64) * 32 + k];
        }
    }
    float za[12], zg[12];
#pragma unroll
    for (int t = 0; t < 12; t++) {
        za[t] = Z1[t * 4096 + b * 128 + l];
        zg[t] = Z1[t * 4096 + b * 128 + 64 + l];
    }
    if (l < 32) hb1[l] = 0.f;
    __builtin_amdgcn_wave_barrier();
    float c = 0.f;
#pragma unroll
    for (int t = 0; t < 12; t++) {
        float d0 = za[t], d1 = zg[t];
#pragma unroll
        for (int k = 0; k < 8; k++) {
            float4 h4 = *(const float4*)&hb1[4 * k];
            d0 += wA[4*k]*h4.x + wA[4*k+1]*h4.y + wA[4*k+2]*h4.z + wA[4*k+3]*h4.w;
            d1 += wB[4*k]*h4.x + wB[4*k+1]*h4.y + wB[4*k+2]*h4.z + wB[4*k+3]*h4.w;
        }
        float e0 = __shfl_xor(d0, 32, 64);
        float e1 = __shfl_xor(d1, 32, 64);
        if (l < 32) {
            c = sigmf(e0) * c + sigmf(d0) * tanhfast(d1);
            float h = sigmf(e1) * tanhfast(c);
            hb1[l] = h;
            h1g[t * 1024 + b * 32 + l] = h;
        }
        __builtin_amdgcn_wave_barrier();
    }
}

// ---------- Wih2 projection: t-parallel, one row per thread ----------
__global__ void __launch_bounds__(512) k_wih2(
    const float* __restrict__ h1g, const void* __restrict__ Wih2r,
    const float* __restrict__ b2i, const float* __restrict__ b2h,
    const int* __restrict__ flags, float* __restrict__ z2g) {
    int tb = blockIdx.x;              // t*32 + b
    int t = tb >> 5, b = tb & 31;
    int r = threadIdx.x;              // 0..511
    __shared__ __align__(16) float h[32];
    if (r < 32) h[r] = h1g[t * 1024 + b * 32 + r];
    __syncthreads();
    float z = b2i[r] + b2h[r];
    const float4* hp = (const float4*)h;
    if (flags[0]) {
        const uint4* wp = (const uint4*)((const uint16_t*)Wih2r + r * 32);
#pragma unroll
        for (int k = 0; k < 4; k++) {
            uint4 u = wp[k];
            float4 h0 = hp[2 * k], h1 = hp[2 * k + 1];
            z += bflo(u.x)*h0.x + bfhi(u.x)*h0.y + bflo(u.y)*h0.z + bfhi(u.y)*h0.w
               + bflo(u.z)*h1.x + bfhi(u.z)*h1.y + bflo(u.w)*h1.z + bfhi(u.w)*h1.w;
        }
    } else {
        const float4* wp = (const float4*)((const float*)Wih2r + r * 32);
#pragma unroll
        for (int k = 0; k < 8; k++) {
            float4 w = wp[k];
            float4 h4 = hp[k];
            z += w.x*h4.x + w.y*h4.y + w.z*h4.z + w.w*h4.w;
        }
    }
    z2g[t * 16384 + b * 512 + r] = z;
}

// ---------- LSTM2: one block (512 thr) per batch, f32-pinned weights ----------
__global__ void __launch_bounds__(512, 1) k_lstm2(
    const float* __restrict__ z2g, const void* __restrict__ Whh2r,
    const int* __restrict__ flags, float* __restrict__ h2l) {
    int b = blockIdx.x, tid = threadIdx.x;
    __shared__ __align__(16) float hb[2][128];
    int bf = flags[0];
    int lane = tid & 63, wv = tid >> 6;
    int kh = lane >> 5;
    int gp = (lane >> 4) & 1;
    int e = wv * 16 + (lane & 15);
    int rA = gp * 256 + e;
    int rB = gp * 256 + 128 + e;

    float wA[64], wB[64];
    if (bf) {
        const uint16_t* W2 = (const uint16_t*)Whh2r;
        const uint4* pA = (const uint4*)(W2 + rA * 128 + kh * 64);
        const uint4* pB = (const uint4*)(W2 + rB * 128 + kh * 64);
#pragma unroll
        for (int k = 0; k < 8; k++) {
            uint4 ua = pA[k], ub = pB[k];
            wA[8*k+0] = bflo(ua.x); wA[8*k+1] = bfhi(ua.x);
            wA[8*k+2] = bflo(ua.y); wA[8*k+3] = bfhi(ua.y);
            wA[8*k+4] = bflo(ua.z); wA[8*k+5] = bfhi(ua.z);
            wA[8*k+6] = bflo(ua.w); wA[8*k+7] = bfhi(ua.w);
            wB[8*k+0] = bflo(ub.x); wB[8*k+1] = bfhi(ub.x);
            wB[8*k+2] = bflo(ub.y); wB[8*k+3] = bfhi(ub.y);
            wB[8*k+4] = bflo(ub.z); wB[8*k+5] = bfhi(ub.z);
            wB[8*k+6] = bflo(ub.w); wB[8*k+7] = bfhi(ub.w);
        }
    } else {
        const float4* pA = (const float4*)((const float*)Whh2r + rA * 128 + kh * 64);
        const float4* pB = (const float4*)((const float*)Whh2r + rB * 128 + kh * 64);
#pragma unroll
        for (int k = 0; k < 16; k++) {
            float4 a = pA[k], c = pB[k];
            wA[4*k+0] = a.x; wA[4*k+1] = a.y; wA[4*k+2] = a.z; wA[4*k+3] = a.w;
            wB[4*k+0] = c.x; wB[4*k+1] = c.y; wB[4*k+2] = c.z; wB[4*k+3] = c.w;
        }
    }
    if (tid < 128) hb[0][tid] = 0.f;
    const float* zb = z2g + b * 512;
    float zA = 0.f, zB = 0.f;
    if (kh == 0) { zA = zb[rA]; zB = zb[rB]; }
    float c2 = 0.f;
    __syncthreads();
#pragma unroll 1
    for (int t = 0; t < 12; t++) {
        float nA = 0.f, nB = 0.f;
        if (t < 11 && kh == 0) {       // prefetch next step's z (L2-hit)
            nA = zb[(t + 1) * 16384 + rA];
            nB = zb[(t + 1) * 16384 + rB];
        }
        const float4* hp = (const float4*)&hb[t & 1][kh * 64];
        float pA = zA, pB = zB;
#pragma unroll
        for (int k = 0; k < 16; k++) {
            float4 h4 = hp[k];
            pA += wA[4*k]*h4.x + wA[4*k+1]*h4.y + wA[4*k+2]*h4.z + wA[4*k+3]*h4.w;
            pB += wB[4*k]*h4.x + wB[4*k+1]*h4.y + wB[4*k+2]*h4.z + wB[4*k+3]*h4.w;
        }
        float sA = pA + __shfl_xor(pA, 32, 64);
        float sB = pB + __shfl_xor(pB, 32, 64);
        float zg_ = __shfl_xor(sA, 16, 64);
        float zo_ = __shfl_xor(sB, 16, 64);
        if (gp == 0) {
            c2 = sigmf(sB) * c2 + sigmf(sA) * tanhfast(zg_);
            float hh = sigmf(zo_) * tanhfast(c2);
            if (kh == 0) {
                hb[(t & 1) ^ 1][e] = hh;
                if (t == 11) h2l[b * 128 + e] = hh;
            }
        }
        __syncthreads();
        zA = nA; zB = nB;
    }
}

// ---------- final linear (dual-path W) ----------
__global__ void __launch_bounds__(256) k_lin(const float* __restrict__ h2l,
                                             const void* __restrict__ Wraw,
                                             const float* __restrict__ bl,
                                             const int* __restrict__ flags,
                                             void* __restrict__ outv) {
    __shared__ float hl[8 * 128];
    int bg = blockIdx.y;
    for (int i = threadIdx.x; i < 1024; i += 256) hl[i] = h2l[bg * 1024 + i];
    __syncthreads();
    int o = blockIdx.x * 256 + threadIdx.x;
    float bb = bl[o];
    float acc[8];
#pragma unroll
    for (int b = 0; b < 8; b++) acc[b] = bb;
    int bf = flags[0];
    if (bf) {
        const uint4* wp = (const uint4*)((const uint16_t*)Wraw + o * 128);
        for (int k = 0; k < 16; k++) {
            uint4 u = wp[k];
            float w0 = bflo(u.x), w1 = bfhi(u.x), w2 = bflo(u.y), w3 = bfhi(u.y);
            float w4 = bflo(u.z), w5 = bfhi(u.z), w6 = bflo(u.w), w7 = bfhi(u.w);
#pragma unroll
            for (int b = 0; b < 8; b++) {
                const float* h8 = hl + b * 128 + k * 8;
                acc[b] += w0 * h8[0] + w1 * h8[1] + w2 * h8[2] + w3 * h8[3]
                        + w4 * h8[4] + w5 * h8[5] + w6 * h8[6] + w7 * h8[7];
            }
        }
    } else {
        const float4* wp = (const float4*)((const float*)Wraw + o * 128);
        for (int k = 0; k < 32; k++) {
            float4 w = wp[k];
#pragma unroll
            for (int b = 0; b < 8; b++) {
                const float* h4 = hl + b * 128 + k * 4;
                acc[b] += w.x * h4[0] + w.y * h4[1] + w.z * h4[2] + w.w * h4[3];
            }
        }
    }
    if (bf) {
        uint16_t* out = (uint16_t*)outv;
#pragma unroll
        for (int b = 0; b < 8; b++) out[(bg * 8 + b) * 18432 + o] = f2bf(acc[b]);
    } else {
        float* out = (float*)outv;
#pragma unroll
        for (int b = 0; b < 8; b++) out[(bg * 8 + b) * 18432 + o] = acc[b];
    }
}

extern "C" void kernel_launch(void* const* d_in, const int* in_sizes, int n_in,
                              void* d_out, int out_size, void* d_ws, size_t ws_size,
                              hipStream_t stream) {
    int E = in_sizes[1] / 2;

    float* ws = (float*)d_ws;
    int* flags = (int*)ws;          // [0]=bf16 [1]=stride [2]=gcount
    float* cWg   = ws + O_WG;
    float* cAtt  = ws + O_AS;
    float* cBias = ws + O_BIAS;
    float* cBih1 = ws + O_BIH1;
    float* cBhh1 = ws + O_BHH1;
    float* cBih2 = ws + O_BIH2;
    float* cBhh2 = ws + O_BHH2;
    float* cBlin = ws + O_BLIN;
    float* cP    = ws + O_P;

    float* base = ws + O_END;
    float* a_s  = base;                            // 524288
    float* a_d  = a_s + 524288;                    // 524288
    int* deg    = (int*)(a_d + 524288);            // 65536
    int* offs   = deg + 65536;                     // 65536
    int* rank   = offs + 65536;                    // E
    int* ssrc   = rank + E;                        // E
    float* gT   = (float*)(ssrc + E);              // 786432
    float* Z1   = gT + 786432;                     // 49152
    float* h2l  = Z1 + 49152;                      // 4096
    float* h1g  = h2l + 4096;                      // 12288  (12*32*32)
    float* z2g  = h1g + 12288;                     // 196608 (12*32*512)
    float* rec  = z2g + 196608;                    // 524288 (65536 * 8 dwords)
    size_t needed = (size_t)((rec + 524288) - ws) * 4;
    if (ws_size < needed) return;

    k_pre<<<256, 256, 0, stream>>>(d_in[0], (const int*)d_in[1],
                                   d_in[2], d_in[3], d_in[4], d_in[5],
                                   d_in[8], d_in[9], d_in[12], d_in[13], d_in[15],
                                   ws, deg);
    k_nfa<<<2048, 256, 0, stream>>>(d_in[0], cWg, cAtt, flags,
                                    (const int*)d_in[1], E, deg, rank,
                                    a_s, a_d, rec);
    k_scan<<<256, 256, 0, stream>>>(deg, offs, flags + 2, cWg, cAtt, cP);
    k_scatter<<<(E + 255) / 256, 256, 0, stream>>>((const int*)d_in[1], E, flags,
                                                   offs, rank, ssrc);
    k_agg<<<NTOT / 4, 256, 0, stream>>>(d_in[0], cWg, a_s, a_d, offs, deg, ssrc,
                                        cBias, flags, rec, cP, gT);
    k_z1<<<96, 256, 0, stream>>>(gT, d_in[6], cBih1, cBhh1, flags, Z1);
    k_lstm1<<<32, 64, 0, stream>>>(Z1, d_in[7], flags, h1g);
    k_wih2<<<384, 512, 0, stream>>>(h1g, d_in[10], cBih2, cBhh2, flags, z2g);
    k_lstm2<<<32, 512, 0, stream>>>(z2g, d_in[11], flags, h2l);
    k_lin<<<dim3(72, 4), 256, 0, stream>>>(h2l, d_in[14], cBlin, flags, d_out);
}